// Round 2
// baseline (303.215 us; speedup 1.0000x reference)
//
#include <hip/hip_runtime.h>
#include <hip/hip_bf16.h>

#define NROWS 8192
#define DDIM 64
#define F4PER (NROWS * NROWS / 4)     /* float4 elements per adj matrix */
#define WLCAP 524288                  /* worklist capacity (events) */

typedef __attribute__((ext_vector_type(8))) short short8v;
typedef __attribute__((ext_vector_type(4))) float f32x4;

#define K2CONST 2.885390081777927f  /* log2(e)/TAU, TAU=0.5 */
#define EPSC 1e-8f

// ---------------- Kernel 1: row L2-normalize + diagonals ----------------
__global__ __launch_bounds__(256) void k_normalize(
    const float* __restrict__ z, const float* __restrict__ za,
    float* __restrict__ zn, float* __restrict__ zan, __hip_bfloat16* __restrict__ Pb,
    float* __restrict__ dI1, float* __restrict__ dI2, float* __restrict__ dX) {
  int wid = (blockIdx.x * blockDim.x + threadIdx.x) >> 6;
  int lane = threadIdx.x & 63;
  if (wid >= NROWS) return;
  float x = z[wid * DDIM + lane];
  float y = za[wid * DDIM + lane];
  float sx = x * x, sy = y * y, sxy = x * y;
  for (int m = 1; m < 64; m <<= 1) {
    sx  += __shfl_xor(sx, m);
    sy  += __shfl_xor(sy, m);
    sxy += __shfl_xor(sxy, m);
  }
  float inx = 1.0f / fmaxf(sqrtf(sx), 1e-12f);
  float iny = 1.0f / fmaxf(sqrtf(sy), 1e-12f);
  float xn = x * inx, yn = y * iny;
  zn[wid * DDIM + lane] = xn;
  zan[wid * DDIM + lane] = yn;
  Pb[wid * DDIM + lane] = __float2bfloat16(xn);
  Pb[(NROWS + wid) * DDIM + lane] = __float2bfloat16(yn);
  if (lane == 0) {
    dI1[wid] = expf(sx * inx * inx * 2.0f);   // /TAU = *2
    dI2[wid] = expf(sy * iny * iny * 2.0f);
    dX[wid]  = expf(sxy * inx * iny * 2.0f);
  }
}

// ---------------- Kernel 2: dense exp-gram row sums via MFMA ----------------
__global__ __launch_bounds__(256) void k_rowsums(
    const __hip_bfloat16* __restrict__ Pb,
    float* __restrict__ sumA, float* __restrict__ sumB) {
  int wave = threadIdx.x >> 6, lane = threadIdx.x & 63;
  int rowbase = blockIdx.x * 256 + wave * 64;  // 64 rows per wave (4 tiles of 16)
  int chunk = blockIdx.y;                      // 16 chunks of 1024 cols
  int colbase = chunk * 1024;
  float* bucket = (chunk < 8) ? sumA : sumB;
  const short8v* P8 = reinterpret_cast<const short8v*>(Pb);

  int r_in = lane & 15, kq = lane >> 4;
  short8v a0[4], a1[4];
#pragma unroll
  for (int rt = 0; rt < 4; rt++) {
    int row = rowbase + rt * 16 + r_in;
    a0[rt] = P8[row * 8 + kq];
    a1[rt] = P8[row * 8 + kq + 4];
  }
  f32x4 s[4];
#pragma unroll
  for (int rt = 0; rt < 4; rt++) s[rt] = (f32x4){0.f, 0.f, 0.f, 0.f};

  for (int ct = 0; ct < 64; ct++) {
    int crow = colbase + ct * 16 + r_in;
    short8v b0 = P8[crow * 8 + kq];
    short8v b1 = P8[crow * 8 + kq + 4];
#pragma unroll
    for (int rt = 0; rt < 4; rt++) {
      f32x4 acc = (f32x4){0.f, 0.f, 0.f, 0.f};
      acc = __builtin_amdgcn_mfma_f32_16x16x32_bf16(a0[rt], b0, acc, 0, 0, 0);
      acc = __builtin_amdgcn_mfma_f32_16x16x32_bf16(a1[rt], b1, acc, 0, 0, 0);
#pragma unroll
      for (int c = 0; c < 4; c++) s[rt][c] += exp2f(acc[c] * K2CONST);
    }
  }
#pragma unroll
  for (int m = 1; m <= 8; m <<= 1) {
#pragma unroll
    for (int rt = 0; rt < 4; rt++) {
#pragma unroll
      for (int c = 0; c < 4; c++) s[rt][c] += __shfl_xor(s[rt][c], m);
    }
  }
  if (r_in == 0) {
#pragma unroll
    for (int rt = 0; rt < 4; rt++) {
#pragma unroll
      for (int c = 0; c < 4; c++) {
        int row = rowbase + rt * 16 + kq * 4 + c;
        atomicAdd(&bucket[row], s[rt][c]);
      }
    }
  }
}

// ---------------- Kernel 3a: stream adj, compact nonzeros to worklist ------
// adj entries are exactly 0.0 or 1.0, density ~0.002 (~268K events total).
__global__ __launch_bounds__(256) void k_scan(
    const float4* __restrict__ a0, const float4* __restrict__ a1,
    unsigned* __restrict__ wl, unsigned* __restrict__ gcount) {
  __shared__ unsigned buf[1024];
  __shared__ unsigned cnt;
  __shared__ unsigned base;
  if (threadIdx.x == 0) cnt = 0;
  __syncthreads();

  const int ITER = (2 * F4PER) / (2048 * 256);  // 64
  int blockbase = blockIdx.x * (ITER * 256);
#pragma unroll 4
  for (int it = 0; it < ITER; it++) {
    int idx = blockbase + it * 256 + threadIdx.x;
    int m = idx >= F4PER;
    int local = idx & (F4PER - 1);
    float4 v = (m ? a1 : a0)[local];
    int i = local >> 11;              // 2048 float4 per row
    int jb = (local & 2047) * 4;
    float vv[4] = {v.x, v.y, v.z, v.w};
#pragma unroll
    for (int k = 0; k < 4; k++) {
      if (vv[k] != 0.f) {
        unsigned pos = atomicAdd(&cnt, 1u);
        if (pos < 1024) buf[pos] = ((unsigned)m << 26) | ((unsigned)i << 13) | (unsigned)(jb + k);
      }
    }
  }
  __syncthreads();
  unsigned n = cnt;
  if (n > 1024) n = 1024;
  if (threadIdx.x == 0) base = atomicAdd(gcount, n);
  __syncthreads();
  for (unsigned t = threadIdx.x; t < n; t += 256) {
    unsigned off = base + t;
    if (off < WLCAP) wl[off] = buf[t];
  }
}

// ---------------- Kernel 3b: process events (wave per pair) ----------------
__global__ __launch_bounds__(256) void k_pairs(
    const unsigned* __restrict__ wl, const unsigned* __restrict__ gcount,
    const float* __restrict__ zn, const float* __restrict__ zan,
    float* __restrict__ sI, float* __restrict__ sJ, float* __restrict__ sC) {
  int wv = (blockIdx.x * blockDim.x + threadIdx.x) >> 6;
  int lane = threadIdx.x & 63;
  int nw = (gridDim.x * blockDim.x) >> 6;
  int count = (int)*gcount;
  if (count > WLCAP) count = WLCAP;
  for (int p = wv; p < count; p += nw) {
    unsigned e = wl[p];
    int m = (int)(e >> 26);
    int i = (int)((e >> 13) & 8191);
    int j = (int)(e & 8191);
    const float* X = m ? zan : zn;
    const float* Y = m ? zn : zan;
    float a = X[i * DDIM + lane];
    float r1 = a * X[j * DDIM + lane];
    float r2 = a * Y[j * DDIM + lane];
#pragma unroll
    for (int mm = 1; mm < 64; mm <<= 1) {
      r1 += __shfl_xor(r1, mm);
      r2 += __shfl_xor(r2, mm);
    }
    if (lane == 0) {
      atomicAdd(&sI[m * NROWS + i], exp2f(r1 * K2CONST));
      atomicAdd(&sJ[m * NROWS + i], exp2f(r2 * K2CONST));
      atomicAdd(&sC[m * NROWS + i], 1.0f);
    }
  }
}

// ---------------- Kernel 4a: per-row loss, partial sums ----------------
__global__ __launch_bounds__(256) void k_final_partial(
    const float* __restrict__ sumA, const float* __restrict__ sumB,
    const float* __restrict__ dI1, const float* __restrict__ dI2,
    const float* __restrict__ dX,
    const float* __restrict__ sI, const float* __restrict__ sJ,
    const float* __restrict__ sC, float* __restrict__ acc) {
  int i = blockIdx.x * blockDim.x + threadIdx.x;  // 32 blocks x 256 = 8192
  float pos1 = dX[i] + sI[i] + sJ[i];
  float den1 = sumA[i] + sumB[i] - dI1[i];
  float l1 = logf(pos1 / (den1 + EPSC) + EPSC) / (2.0f * sC[i] + 1.0f);
  float pos2 = dX[i] + sI[NROWS + i] + sJ[NROWS + i];
  float den2 = sumA[NROWS + i] + sumB[NROWS + i] - dI2[i];
  float l2 = logf(pos2 / (den2 + EPSC) + EPSC) / (2.0f * sC[NROWS + i] + 1.0f);
  float local = l1 + l2;
#pragma unroll
  for (int m = 1; m < 64; m <<= 1) local += __shfl_xor(local, m);
  if ((threadIdx.x & 63) == 0) atomicAdd(acc, local);
}

__global__ void k_finalize(const float* __restrict__ acc, float* __restrict__ out) {
  out[0] = -acc[0] * (0.5f / (float)NROWS);
}

extern "C" void kernel_launch(void* const* d_in, const int* in_sizes, int n_in,
                              void* d_out, int out_size, void* d_ws, size_t ws_size,
                              hipStream_t stream) {
  const float* z       = (const float*)d_in[0];
  const float* za      = (const float*)d_in[1];
  const float* adj     = (const float*)d_in[2];
  const float* adj_aug = (const float*)d_in[3];

  float* ws = (float*)d_ws;
  float* zn  = ws;                                       // 524288
  float* zan = ws + 524288;                              // 524288
  __hip_bfloat16* Pb = (__hip_bfloat16*)(ws + 1048576);  // 1048576 bf16
  float* Z0   = ws + 1572864;   // zeroed region start
  float* sumA = Z0;             // 16384
  float* sumB = Z0 + 16384;     // 16384
  float* sI   = Z0 + 32768;     // 16384
  float* sJ   = Z0 + 49152;     // 16384
  float* sC   = Z0 + 65536;     // 16384
  float* acc  = Z0 + 81920;     // 1
  unsigned* gcount = (unsigned*)(Z0 + 81921);            // 1
  float* dI1 = Z0 + 81922;      // 8192
  float* dI2 = dI1 + 8192;      // 8192
  float* dX  = dI2 + 8192;      // 8192
  unsigned* wl = (unsigned*)(dX + 8192);                 // WLCAP u32 = 2 MB

  hipMemsetAsync(Z0, 0, 81922 * sizeof(float), stream);

  k_normalize<<<2048, 256, 0, stream>>>(z, za, zn, zan, Pb, dI1, dI2, dX);
  k_scan<<<2048, 256, 0, stream>>>((const float4*)adj, (const float4*)adj_aug, wl, gcount);
  dim3 g2(64, 16);
  k_rowsums<<<g2, 256, 0, stream>>>(Pb, sumA, sumB);
  k_pairs<<<1024, 256, 0, stream>>>(wl, gcount, zn, zan, sI, sJ, sC);
  k_final_partial<<<32, 256, 0, stream>>>(sumA, sumB, dI1, dI2, dX, sI, sJ, sC, acc);
  k_finalize<<<1, 1, 0, stream>>>(acc, (float*)d_out);
}

// Round 5
// 223.322 us; speedup vs baseline: 1.3577x; 1.3577x over previous
//
#include <hip/hip_runtime.h>
#include <hip/hip_bf16.h>

#define NROWS 8192
#define DDIM 64
#define F4PER (NROWS * NROWS / 4)     /* float4 elements per adj matrix */

typedef __attribute__((ext_vector_type(8))) short short8v;
typedef __attribute__((ext_vector_type(4))) float f32x4;

#define K2CONST 2.885390081777927f  /* log2(e)/TAU, TAU=0.5 */
#define EPSC 1e-8f

// ---------------- Kernel 1: row L2-normalize + diagonals ----------------
__global__ __launch_bounds__(256) void k_normalize(
    const float* __restrict__ z, const float* __restrict__ za,
    float* __restrict__ zn, float* __restrict__ zan, __hip_bfloat16* __restrict__ Pb,
    float* __restrict__ dI1, float* __restrict__ dI2, float* __restrict__ dX) {
  int wid = (blockIdx.x * blockDim.x + threadIdx.x) >> 6;
  int lane = threadIdx.x & 63;
  if (wid >= NROWS) return;
  float x = z[wid * DDIM + lane];
  float y = za[wid * DDIM + lane];
  float sx = x * x, sy = y * y, sxy = x * y;
  for (int m = 1; m < 64; m <<= 1) {
    sx  += __shfl_xor(sx, m);
    sy  += __shfl_xor(sy, m);
    sxy += __shfl_xor(sxy, m);
  }
  float inx = 1.0f / fmaxf(sqrtf(sx), 1e-12f);
  float iny = 1.0f / fmaxf(sqrtf(sy), 1e-12f);
  float xn = x * inx, yn = y * iny;
  zn[wid * DDIM + lane] = xn;
  zan[wid * DDIM + lane] = yn;
  Pb[wid * DDIM + lane] = __float2bfloat16(xn);
  Pb[(NROWS + wid) * DDIM + lane] = __float2bfloat16(yn);
  if (lane == 0) {
    dI1[wid] = expf(sx * inx * inx * 2.0f);   // /TAU = *2
    dI2[wid] = expf(sy * iny * iny * 2.0f);
    dX[wid]  = expf(sxy * inx * iny * 2.0f);
  }
}

// ---------------- Mega kernel: scan+pairs blocks interleaved with rowsums --
// bid%3<2  -> scan role (2048 blocks): stream 256KB of adj with 8-deep batched
//             loads, compact nonzeros to LDS, process events at block end.
// bid%3==2 -> rowsum role (1024 blocks): MFMA exp-gram row sums.
__global__ __launch_bounds__(256) void k_mega(
    const float4* __restrict__ a0, const float4* __restrict__ a1,
    const __hip_bfloat16* __restrict__ Pb,
    const float* __restrict__ zn, const float* __restrict__ zan,
    float* __restrict__ sumA, float* __restrict__ sumB,
    float* __restrict__ sI, float* __restrict__ sJ, float* __restrict__ sC) {
  __shared__ unsigned buf[1024];
  __shared__ unsigned cnt;
  int bid = blockIdx.x;
  int r3 = bid % 3;
  int g = bid / 3;
  int wave = threadIdx.x >> 6, lane = threadIdx.x & 63;

  if (r3 < 2) {
    // ================= scan role =================
    int s = g * 2 + r3;               // 0..2047
    if (threadIdx.x == 0) cnt = 0;
    __syncthreads();
    int m = s >> 10;                  // which matrix
    const float4* A = m ? a1 : a0;
    int base = (s & 1023) * 16384;    // float4 index within matrix

    for (int it = 0; it < 8; it++) {
      int ib = base + it * 2048 + threadIdx.x;
      float4 v[8];
#pragma unroll
      for (int u = 0; u < 8; u++) v[u] = A[ib + u * 256];  // 8 loads in flight
#pragma unroll
      for (int u = 0; u < 8; u++) {
        int idx = ib + u * 256;
        unsigned i = (unsigned)(idx >> 11);        // 2048 float4 per row
        unsigned jb = (unsigned)((idx & 2047) << 2);
        if (v[u].x != 0.f) { unsigned p = atomicAdd(&cnt, 1u); if (p < 1024) buf[p] = (i << 13) | jb; }
        if (v[u].y != 0.f) { unsigned p = atomicAdd(&cnt, 1u); if (p < 1024) buf[p] = (i << 13) | (jb + 1); }
        if (v[u].z != 0.f) { unsigned p = atomicAdd(&cnt, 1u); if (p < 1024) buf[p] = (i << 13) | (jb + 2); }
        if (v[u].w != 0.f) { unsigned p = atomicAdd(&cnt, 1u); if (p < 1024) buf[p] = (i << 13) | (jb + 3); }
      }
    }
    __syncthreads();
    unsigned n = cnt; if (n > 1024) n = 1024;
    const float* X = m ? zan : zn;    // intra partner
    const float* Y = m ? zn : zan;    // inter partner
    for (unsigned e = wave; e < n; e += 4) {
      unsigned ev = buf[e];
      int i = (int)(ev >> 13);
      int j = (int)(ev & 8191);
      float a = X[i * DDIM + lane];
      float r1 = a * X[j * DDIM + lane];
      float r2 = a * Y[j * DDIM + lane];
#pragma unroll
      for (int mm = 1; mm < 64; mm <<= 1) {
        r1 += __shfl_xor(r1, mm);
        r2 += __shfl_xor(r2, mm);
      }
      if (lane == 0) {
        atomicAdd(&sI[m * NROWS + i], exp2f(r1 * K2CONST));
        atomicAdd(&sJ[m * NROWS + i], exp2f(r2 * K2CONST));
        atomicAdd(&sC[m * NROWS + i], 1.0f);
      }
    }
  } else {
    // ================= rowsum role =================
    int q = g;                        // 0..1023
    int chunk = q >> 6;               // 0..15
    int rowbase = (q & 63) * 256 + wave * 64;
    int colbase = chunk * 1024;
    float* bucket = (chunk < 8) ? sumA : sumB;
    const short8v* P8 = reinterpret_cast<const short8v*>(Pb);

    int r_in = lane & 15, kq = lane >> 4;
    short8v A0[4], A1[4];
#pragma unroll
    for (int rt = 0; rt < 4; rt++) {
      int row = rowbase + rt * 16 + r_in;
      A0[rt] = P8[row * 8 + kq];
      A1[rt] = P8[row * 8 + kq + 4];
    }
    f32x4 sacc[4];
#pragma unroll
    for (int rt = 0; rt < 4; rt++) sacc[rt] = (f32x4){0.f, 0.f, 0.f, 0.f};

    for (int ct = 0; ct < 64; ct++) {
      int crow = colbase + ct * 16 + r_in;
      short8v b0 = P8[crow * 8 + kq];
      short8v b1 = P8[crow * 8 + kq + 4];
#pragma unroll
      for (int rt = 0; rt < 4; rt++) {
        f32x4 acc = (f32x4){0.f, 0.f, 0.f, 0.f};
        acc = __builtin_amdgcn_mfma_f32_16x16x32_bf16(A0[rt], b0, acc, 0, 0, 0);
        acc = __builtin_amdgcn_mfma_f32_16x16x32_bf16(A1[rt], b1, acc, 0, 0, 0);
#pragma unroll
        for (int c = 0; c < 4; c++) sacc[rt][c] += exp2f(acc[c] * K2CONST);
      }
    }
#pragma unroll
    for (int mm = 1; mm <= 8; mm <<= 1) {
#pragma unroll
      for (int rt = 0; rt < 4; rt++) {
#pragma unroll
        for (int c = 0; c < 4; c++) sacc[rt][c] += __shfl_xor(sacc[rt][c], mm);
      }
    }
    if (r_in == 0) {
#pragma unroll
      for (int rt = 0; rt < 4; rt++) {
#pragma unroll
        for (int c = 0; c < 4; c++) {
          int row = rowbase + rt * 16 + kq * 4 + c;
          atomicAdd(&bucket[row], sacc[rt][c]);
        }
      }
    }
  }
}

// ---------------- Final: per-row loss, partial sums ----------------
__global__ __launch_bounds__(256) void k_final_partial(
    const float* __restrict__ sumA, const float* __restrict__ sumB,
    const float* __restrict__ dI1, const float* __restrict__ dI2,
    const float* __restrict__ dX,
    const float* __restrict__ sI, const float* __restrict__ sJ,
    const float* __restrict__ sC, float* __restrict__ acc) {
  int i = blockIdx.x * blockDim.x + threadIdx.x;  // 32 blocks x 256 = 8192
  float pos1 = dX[i] + sI[i] + sJ[i];
  float den1 = sumA[i] + sumB[i] - dI1[i];
  float l1 = logf(pos1 / (den1 + EPSC) + EPSC) / (2.0f * sC[i] + 1.0f);
  float pos2 = dX[i] + sI[NROWS + i] + sJ[NROWS + i];
  float den2 = sumA[NROWS + i] + sumB[NROWS + i] - dI2[i];
  float l2 = logf(pos2 / (den2 + EPSC) + EPSC) / (2.0f * sC[NROWS + i] + 1.0f);
  float local = l1 + l2;
#pragma unroll
  for (int m = 1; m < 64; m <<= 1) local += __shfl_xor(local, m);
  if ((threadIdx.x & 63) == 0) atomicAdd(acc, local);
}

__global__ void k_finalize(const float* __restrict__ acc, float* __restrict__ out) {
  out[0] = -acc[0] * (0.5f / (float)NROWS);
}

extern "C" void kernel_launch(void* const* d_in, const int* in_sizes, int n_in,
                              void* d_out, int out_size, void* d_ws, size_t ws_size,
                              hipStream_t stream) {
  const float* z       = (const float*)d_in[0];
  const float* za      = (const float*)d_in[1];
  const float* adj     = (const float*)d_in[2];
  const float* adj_aug = (const float*)d_in[3];

  float* ws = (float*)d_ws;
  float* zn  = ws;                                       // 524288
  float* zan = ws + 524288;                              // 524288
  __hip_bfloat16* Pb = (__hip_bfloat16*)(ws + 1048576);  // 1048576 bf16
  float* Z0   = ws + 1572864;   // zeroed region start
  float* sumA = Z0;             // 16384
  float* sumB = Z0 + 16384;     // 16384
  float* sI   = Z0 + 32768;     // 16384
  float* sJ   = Z0 + 49152;     // 16384
  float* sC   = Z0 + 65536;     // 16384
  float* acc  = Z0 + 81920;     // 1
  float* dI1  = Z0 + 81921;     // 8192
  float* dI2  = dI1 + 8192;     // 8192
  float* dX   = dI2 + 8192;     // 8192

  hipMemsetAsync(Z0, 0, 81921 * sizeof(float), stream);

  k_normalize<<<2048, 256, 0, stream>>>(z, za, zn, zan, Pb, dI1, dI2, dX);
  k_mega<<<3072, 256, 0, stream>>>((const float4*)adj, (const float4*)adj_aug,
                                   Pb, zn, zan, sumA, sumB, sI, sJ, sC);
  k_final_partial<<<32, 256, 0, stream>>>(sumA, sumB, dI1, dI2, dX, sI, sJ, sC, acc);
  k_finalize<<<1, 1, 0, stream>>>(acc, (float*)d_out);
}

// Round 6
// 202.219 us; speedup vs baseline: 1.4994x; 1.1044x over previous
//
#include <hip/hip_runtime.h>
#include <hip/hip_bf16.h>

#define NROWS 8192
#define DDIM 64

typedef __attribute__((ext_vector_type(8))) short short8v;
typedef __attribute__((ext_vector_type(4))) float f32x4;

#define K2CONST 2.885390081777927f  /* log2(e)/TAU, TAU=0.5 */
#define EPSC 1e-8f

// ---------------- Kernel 1: row L2-normalize (bf16 P) + diagonals ----------
__global__ __launch_bounds__(256) void k_normalize(
    const float* __restrict__ z, const float* __restrict__ za,
    __hip_bfloat16* __restrict__ Pb,
    float* __restrict__ dI1, float* __restrict__ dI2, float* __restrict__ dX) {
  int wid = (blockIdx.x * blockDim.x + threadIdx.x) >> 6;
  int lane = threadIdx.x & 63;
  if (wid >= NROWS) return;
  float x = z[wid * DDIM + lane];
  float y = za[wid * DDIM + lane];
  float sx = x * x, sy = y * y, sxy = x * y;
  for (int m = 1; m < 64; m <<= 1) {
    sx  += __shfl_xor(sx, m);
    sy  += __shfl_xor(sy, m);
    sxy += __shfl_xor(sxy, m);
  }
  float inx = 1.0f / fmaxf(sqrtf(sx), 1e-12f);
  float iny = 1.0f / fmaxf(sqrtf(sy), 1e-12f);
  Pb[wid * DDIM + lane] = __float2bfloat16(x * inx);
  Pb[(NROWS + wid) * DDIM + lane] = __float2bfloat16(y * iny);
  if (lane == 0) {
    dI1[wid] = expf(sx * inx * inx * 2.0f);   // /TAU = *2
    dI2[wid] = expf(sy * iny * iny * 2.0f);
    dX[wid]  = expf(sxy * inx * iny * 2.0f);
  }
}

// ---------------- Kernel 2: fused gram row-sums + adj-masked sums ----------
// P = [zn; zan] (16384 x 64) bf16. Wave handles 32 gram rows x 512 cols(mod N),
// covering BOTH column quadrants (j and j+8192) so each adj element is loaded
// exactly once and applied to both exp'd gram entries.
// Outputs per gram row r: sumA[r] (dense, j<N), sumB[r] (dense, j>=N),
//                         mI[r] (masked, j<N), mJ[r] (masked, j>=N),
//                         cnt[r] (= row degree of the mask).
__global__ __launch_bounds__(256) void k_fused(
    const __hip_bfloat16* __restrict__ Pb,
    const float* __restrict__ adj, const float* __restrict__ adj_aug,
    float* __restrict__ sumA, float* __restrict__ sumB,
    float* __restrict__ mI, float* __restrict__ mJ, float* __restrict__ cnt) {
  int wave = threadIdx.x >> 6, lane = threadIdx.x & 63;
  int r_in = lane & 15, kq = lane >> 4;
  int rb = blockIdx.x >> 4;                 // 128 row-blocks of 128 rows
  int cb = blockIdx.x & 15;                 // 16 col-blocks of 512 cols
  int rowbase = rb * 128 + wave * 32;       // this wave: 32 gram rows
  int cbase = cb * 512;
  const float* ADJ = (rowbase < NROWS) ? adj : adj_aug;
  int arow0 = rowbase & (NROWS - 1);
  // per-lane adj base: row (arow0 + kq*4), col (cbase + r_in)
  const float* adjp = ADJ + (size_t)(arow0 + kq * 4) * NROWS + cbase + r_in;

  const short8v* P8 = reinterpret_cast<const short8v*>(Pb);
  short8v a0[2], a1[2];
#pragma unroll
  for (int rt = 0; rt < 2; rt++) {
    int row = rowbase + rt * 16 + r_in;
    a0[rt] = P8[row * 8 + kq];
    a1[rt] = P8[row * 8 + kq + 4];
  }
  f32x4 sA[2], sB[2], mA[2], mB[2], cn[2];
#pragma unroll
  for (int rt = 0; rt < 2; rt++) {
    sA[rt] = (f32x4){0.f, 0.f, 0.f, 0.f};
    sB[rt] = (f32x4){0.f, 0.f, 0.f, 0.f};
    mA[rt] = (f32x4){0.f, 0.f, 0.f, 0.f};
    mB[rt] = (f32x4){0.f, 0.f, 0.f, 0.f};
    cn[rt] = (f32x4){0.f, 0.f, 0.f, 0.f};
  }

  for (int ct = 0; ct < 32; ct++) {
    int colA = cbase + ct * 16 + r_in;      // P row for quadrant A (j < N)
    short8v b0 = P8[colA * 8 + kq];
    short8v b1 = P8[colA * 8 + kq + 4];
    short8v c0 = P8[(colA + NROWS) * 8 + kq];   // quadrant B (j >= N)
    short8v c1 = P8[(colA + NROWS) * 8 + kq + 4];
    // adj values for this wave's C fragments: row kq*4+c (+rt*16), col r_in (+ct*16)
    float av[2][4];
#pragma unroll
    for (int rt = 0; rt < 2; rt++)
#pragma unroll
      for (int c = 0; c < 4; c++)
        av[rt][c] = adjp[(size_t)(rt * 16 + c) * NROWS + ct * 16];
#pragma unroll
    for (int rt = 0; rt < 2; rt++) {
      f32x4 accA = (f32x4){0.f, 0.f, 0.f, 0.f};
      accA = __builtin_amdgcn_mfma_f32_16x16x32_bf16(a0[rt], b0, accA, 0, 0, 0);
      accA = __builtin_amdgcn_mfma_f32_16x16x32_bf16(a1[rt], b1, accA, 0, 0, 0);
      f32x4 accB = (f32x4){0.f, 0.f, 0.f, 0.f};
      accB = __builtin_amdgcn_mfma_f32_16x16x32_bf16(a0[rt], c0, accB, 0, 0, 0);
      accB = __builtin_amdgcn_mfma_f32_16x16x32_bf16(a1[rt], c1, accB, 0, 0, 0);
#pragma unroll
      for (int c = 0; c < 4; c++) {
        float e0 = exp2f(accA[c] * K2CONST);
        float e1 = exp2f(accB[c] * K2CONST);
        float a = av[rt][c];
        sA[rt][c] += e0;
        sB[rt][c] += e1;
        mA[rt][c] += a * e0;
        mB[rt][c] += a * e1;
        cn[rt][c] += a;
      }
    }
  }
  // reduce across the 16 lanes (r_in) sharing kq — they span the 16 cols
#pragma unroll
  for (int m = 1; m <= 8; m <<= 1) {
#pragma unroll
    for (int rt = 0; rt < 2; rt++) {
#pragma unroll
      for (int c = 0; c < 4; c++) {
        sA[rt][c] += __shfl_xor(sA[rt][c], m);
        sB[rt][c] += __shfl_xor(sB[rt][c], m);
        mA[rt][c] += __shfl_xor(mA[rt][c], m);
        mB[rt][c] += __shfl_xor(mB[rt][c], m);
        cn[rt][c] += __shfl_xor(cn[rt][c], m);
      }
    }
  }
  if (r_in == 0) {
#pragma unroll
    for (int rt = 0; rt < 2; rt++) {
#pragma unroll
      for (int c = 0; c < 4; c++) {
        int row = rowbase + rt * 16 + kq * 4 + c;
        atomicAdd(&sumA[row], sA[rt][c]);
        atomicAdd(&sumB[row], sB[rt][c]);
        atomicAdd(&mI[row], mA[rt][c]);
        atomicAdd(&mJ[row], mB[rt][c]);
        atomicAdd(&cnt[row], cn[rt][c]);
      }
    }
  }
}

// ---------------- Final: per-row loss, partial sums ----------------
__global__ __launch_bounds__(256) void k_final_partial(
    const float* __restrict__ sumA, const float* __restrict__ sumB,
    const float* __restrict__ dI1, const float* __restrict__ dI2,
    const float* __restrict__ dX,
    const float* __restrict__ mI, const float* __restrict__ mJ,
    const float* __restrict__ cnt, float* __restrict__ acc) {
  int i = blockIdx.x * blockDim.x + threadIdx.x;  // 32 blocks x 256 = 8192
  float pos1 = dX[i] + mI[i] + mJ[i];
  float den1 = sumA[i] + sumB[i] - dI1[i];
  float l1 = logf(pos1 / (den1 + EPSC) + EPSC) / (2.0f * cnt[i] + 1.0f);
  float pos2 = dX[i] + mI[NROWS + i] + mJ[NROWS + i];
  float den2 = sumA[NROWS + i] + sumB[NROWS + i] - dI2[i];
  float l2 = logf(pos2 / (den2 + EPSC) + EPSC) / (2.0f * cnt[NROWS + i] + 1.0f);
  float local = l1 + l2;
#pragma unroll
  for (int m = 1; m < 64; m <<= 1) local += __shfl_xor(local, m);
  if ((threadIdx.x & 63) == 0) atomicAdd(acc, local);
}

__global__ void k_finalize(const float* __restrict__ acc, float* __restrict__ out) {
  out[0] = -acc[0] * (0.5f / (float)NROWS);
}

extern "C" void kernel_launch(void* const* d_in, const int* in_sizes, int n_in,
                              void* d_out, int out_size, void* d_ws, size_t ws_size,
                              hipStream_t stream) {
  const float* z       = (const float*)d_in[0];
  const float* za      = (const float*)d_in[1];
  const float* adj     = (const float*)d_in[2];
  const float* adj_aug = (const float*)d_in[3];

  float* ws = (float*)d_ws;
  __hip_bfloat16* Pb = (__hip_bfloat16*)ws;   // 16384*64 bf16 = 524288 f32 slots
  float* Z0   = ws + 524288;    // zeroed region: 5*16384 + 1 floats
  float* sumA = Z0;             // 16384
  float* sumB = Z0 + 16384;     // 16384
  float* mI   = Z0 + 32768;     // 16384
  float* mJ   = Z0 + 49152;     // 16384
  float* cnt  = Z0 + 65536;     // 16384
  float* acc  = Z0 + 81920;     // 1
  float* dI1  = Z0 + 81921;     // 8192
  float* dI2  = dI1 + 8192;     // 8192
  float* dX   = dI2 + 8192;     // 8192

  hipMemsetAsync(Z0, 0, 81921 * sizeof(float), stream);

  k_normalize<<<2048, 256, 0, stream>>>(z, za, Pb, dI1, dI2, dX);
  k_fused<<<2048, 256, 0, stream>>>(Pb, adj, adj_aug, sumA, sumB, mI, mJ, cnt);
  k_final_partial<<<32, 256, 0, stream>>>(sumA, sumB, dI1, dI2, dX, mI, mJ, cnt, acc);
  k_finalize<<<1, 1, 0, stream>>>(acc, (float*)d_out);
}